// Round 12
// baseline (400.373 us; speedup 1.0000x reference)
//
#include <hip/hip_runtime.h>
#include <stdint.h>

#define N_NODES 10000
#define F_IN    512
#define E_DIM   256
#define H0D     512
#define H1D     256
#define N_EDGES 160000
#define T_TOT   (N_EDGES + N_NODES)   // 170000

#define MARGIN_LK 4e-3f
#define MARGIN_L  4e-3f
#define LIST_CAP 60000
#define FIX_GRID 512
#define LP 40                       // padded LDS row stride in f16 (80B)

typedef _Float16 f16;
typedef __attribute__((ext_vector_type(8))) _Float16 f16x8;
typedef __attribute__((ext_vector_type(4))) _Float16 f16x4;
typedef __attribute__((ext_vector_type(4))) float f32x4;

// monotone map fp32 -> uint32 (order-preserving)
__device__ __forceinline__ unsigned int f2ord(float f) {
    unsigned int u = __float_as_uint(f);
    return (u & 0x80000000u) ? ~u : (u | 0x80000000u);
}
__device__ __forceinline__ float ord2f(unsigned int o) {
    unsigned int u = (o & 0x80000000u) ? (o & 0x7fffffffu) : ~o;
    return __uint_as_float(u);
}

__device__ __forceinline__ int seg_of(int t, const int* esrc) {
    return (t < N_EDGES) ? esrc[t] : t - N_EDGES;
}

// ---------------------------------------------------------------------------
// K_PREP_ALL: weight matrices -> chunked n-major split-f16 images.
// blocks 0-15: We; 16-31: W1; 32-63: W0 (4 groups x 8 chunks).
// ---------------------------------------------------------------------------
__global__ void k_prep_all(const float* __restrict__ We,
                           const float* __restrict__ W1,
                           const float* __restrict__ W0,
                           f16* __restrict__ WeC_h, f16* __restrict__ WeC_l,
                           f16* __restrict__ W1C_h, f16* __restrict__ W1C_l,
                           f16* __restrict__ W0C_h, f16* __restrict__ W0C_l) {
    int b = blockIdx.x;
    int n = threadIdx.x;
    const float* W;
    int ld, rowoff, colbase, c;
    f16 *dh_base, *dl_base;
    if (b < 16) {
        W = We; ld = E_DIM; rowoff = 0; colbase = 0; c = b;
        dh_base = WeC_h; dl_base = WeC_l;
    } else if (b < 32) {
        W = W1; ld = H1D; rowoff = 0; colbase = 0; c = b - 16;
        dh_base = W1C_h; dl_base = W1C_l;
    } else {
        int g = (b - 32) >> 3; c = (b - 32) & 7;
        rowoff = (g >= 2) ? 256 : 0; colbase = (g & 1) * 256;
        W = W0; ld = H0D;
        dh_base = W0C_h + (size_t)g * 8 * 256 * 32;
        dl_base = W0C_l + (size_t)g * 8 * 256 * 32;
    }
    f16* dh = dh_base + ((size_t)c * 256 + n) * 32;
    f16* dl = dl_base + ((size_t)c * 256 + n) * 32;
    const float* src = W + (size_t)(rowoff + c * 32) * ld + colbase + n;
#pragma unroll
    for (int kk = 0; kk < 32; kk++) {
        float w = src[(size_t)kk * ld];
        f16 h = (f16)w;
        f16 l = (f16)(w - (float)h);
        dh[kk] = h;
        dl[kk] = l;
    }
}

// ---------------------------------------------------------------------------
// K1: Z = feature @ We + be (3-term split-f16, fp32-class);  out = relu(Z)
// 32-row tiles, register-B, A-only LDS.
// ---------------------------------------------------------------------------
__global__ __launch_bounds__(256, 2) void k1_split(
        const float* __restrict__ feat, const f16* __restrict__ Bh_g,
        const f16* __restrict__ Bl_g, const float* __restrict__ be,
        float* __restrict__ Z, float* __restrict__ out) {
    __shared__ f16 Ah[32 * LP], Al_[32 * LP];
    const int tid = threadIdx.x;
    const int wave = tid >> 6, lane = tid & 63;
    const int quad = lane >> 4, l15 = lane & 15;
    const int mbase = blockIdx.x * 32;
    const int arow = tid >> 3, apos = tid & 7;
    const int gm_a = mbase + arow;
    const float* Arow = feat + (size_t)gm_a * F_IN + apos * 4;
    const bool rowok = (gm_a < N_NODES);

    f32x4 acc[2][4];
#pragma unroll
    for (int i = 0; i < 2; i++)
#pragma unroll
        for (int j = 0; j < 4; j++) acc[i][j] = (f32x4){0.f, 0.f, 0.f, 0.f};

    f16x8 bh[4], bl[4], bhn[4], bln[4];
#pragma unroll
    for (int ct = 0; ct < 4; ct++) {
        size_t o = ((size_t)(wave * 64 + ct * 16 + l15)) * 32 + quad * 8;
        bh[ct] = *(const f16x8*)(Bh_g + o);
        bl[ct] = *(const f16x8*)(Bl_g + o);
    }
    float4 a = rowok ? *(const float4*)(Arow) : make_float4(0.f, 0.f, 0.f, 0.f);

    for (int c = 0; c < 16; c++) {
        f16x4 hv, lv;
        float av[4] = {a.x, a.y, a.z, a.w};
#pragma unroll
        for (int q = 0; q < 4; q++) {
            f16 h = (f16)av[q];
            hv[q] = h;
            lv[q] = (f16)(av[q] - (float)h);
        }
        *(f16x4*)(Ah + arow * LP + apos * 4) = hv;
        *(f16x4*)(Al_ + arow * LP + apos * 4) = lv;
        if (c + 1 < 16) {
            a = rowok ? *(const float4*)(Arow + (c + 1) * 32)
                      : make_float4(0.f, 0.f, 0.f, 0.f);
#pragma unroll
            for (int ct = 0; ct < 4; ct++) {
                size_t o = ((size_t)((c + 1) * 256 + wave * 64 + ct * 16 + l15)) * 32 + quad * 8;
                bhn[ct] = *(const f16x8*)(Bh_g + o);
                bln[ct] = *(const f16x8*)(Bl_g + o);
            }
        }
        __syncthreads();
        f16x8 afh[2], afl[2];
#pragma unroll
        for (int rt = 0; rt < 2; rt++) {
            afh[rt] = *(const f16x8*)(Ah + (rt * 16 + l15) * LP + quad * 8);
            afl[rt] = *(const f16x8*)(Al_ + (rt * 16 + l15) * LP + quad * 8);
        }
#pragma unroll
        for (int rt = 0; rt < 2; rt++)
#pragma unroll
            for (int ct = 0; ct < 4; ct++) {
                acc[rt][ct] = __builtin_amdgcn_mfma_f32_16x16x32_f16(
                    afh[rt], bh[ct], acc[rt][ct], 0, 0, 0);
                acc[rt][ct] = __builtin_amdgcn_mfma_f32_16x16x32_f16(
                    afl[rt], bh[ct], acc[rt][ct], 0, 0, 0);
                acc[rt][ct] = __builtin_amdgcn_mfma_f32_16x16x32_f16(
                    afh[rt], bl[ct], acc[rt][ct], 0, 0, 0);
            }
        __syncthreads();
#pragma unroll
        for (int ct = 0; ct < 4; ct++) { bh[ct] = bhn[ct]; bl[ct] = bln[ct]; }
    }

#pragma unroll
    for (int ct = 0; ct < 4; ct++) {
        int n = wave * 64 + ct * 16 + l15;
        float bb = be[n];
#pragma unroll
        for (int rt = 0; rt < 2; rt++)
#pragma unroll
            for (int reg = 0; reg < 4; reg++) {
                int gm = mbase + rt * 16 + quad * 4 + reg;
                if (gm < N_NODES) {
                    float z = acc[rt][ct][reg] + bb;
                    Z[(size_t)gm * E_DIM + n] = z;
                    out[(size_t)gm * E_DIM + n] = fmaxf(z, 0.f);
                }
            }
    }
}

// ---------------------------------------------------------------------------
// K2: P = emb @ W0[0:256,:] + b0 ; Q = emb @ W0[256:512,:]  (3-term exact)
// Stores SPLIT f16: Ph/Pl and Qh/Ql (Ph+Pl reconstructs fp32 P to ~2^-22).
// ---------------------------------------------------------------------------
__global__ __launch_bounds__(256, 3) void k2_split(
        const float* __restrict__ emb, const f16* __restrict__ W0Ch,
        const f16* __restrict__ W0Cl, const float* __restrict__ b0,
        f16* __restrict__ Ph, f16* __restrict__ Pl,
        f16* __restrict__ Qh, f16* __restrict__ Ql) {
    __shared__ f16 Ah[64 * LP], Al_[64 * LP];
    const int tid = threadIdx.x;
    const int wave = tid >> 6, lane = tid & 63;
    const int quad = lane >> 4, l15 = lane & 15;
    const int mbase = blockIdx.x * 64;
    const int g = blockIdx.y;
    const int isQ = (g >= 2);
    const int colbase = (g & 1) * 256;
    const int arow = tid >> 2, akp = tid & 3;
    const int gm_a = mbase + arow;
    const float* Arow = emb + (size_t)gm_a * E_DIM + akp * 8;
    const bool rowok = (gm_a < N_NODES);
    const f16* Bh_g = W0Ch + (size_t)g * 8 * 256 * 32;
    const f16* Bl_g = W0Cl + (size_t)g * 8 * 256 * 32;

    f32x4 acc[4][4];
#pragma unroll
    for (int i = 0; i < 4; i++)
#pragma unroll
        for (int j = 0; j < 4; j++) acc[i][j] = (f32x4){0.f, 0.f, 0.f, 0.f};

    f16x8 bh[4], bl[4], bhn[4], bln[4];
#pragma unroll
    for (int ct = 0; ct < 4; ct++) {
        size_t o = ((size_t)(wave * 64 + ct * 16 + l15)) * 32 + quad * 8;
        bh[ct] = *(const f16x8*)(Bh_g + o);
        bl[ct] = *(const f16x8*)(Bl_g + o);
    }
    float4 a0 = make_float4(0.f, 0.f, 0.f, 0.f), a1 = a0;
    if (rowok) { a0 = *(const float4*)(Arow); a1 = *(const float4*)(Arow + 4); }

    for (int c = 0; c < 8; c++) {
        f16x8 hv, lv;
        float av[8] = {a0.x, a0.y, a0.z, a0.w, a1.x, a1.y, a1.z, a1.w};
#pragma unroll
        for (int q = 0; q < 8; q++) {
            f16 h = (f16)av[q];
            hv[q] = h;
            lv[q] = (f16)(av[q] - (float)h);
        }
        *(f16x8*)(Ah + arow * LP + akp * 8) = hv;
        *(f16x8*)(Al_ + arow * LP + akp * 8) = lv;
        if (c + 1 < 8) {
            if (rowok) {
                a0 = *(const float4*)(Arow + (c + 1) * 32);
                a1 = *(const float4*)(Arow + (c + 1) * 32 + 4);
            }
#pragma unroll
            for (int ct = 0; ct < 4; ct++) {
                size_t o = ((size_t)((c + 1) * 256 + wave * 64 + ct * 16 + l15)) * 32 + quad * 8;
                bhn[ct] = *(const f16x8*)(Bh_g + o);
                bln[ct] = *(const f16x8*)(Bl_g + o);
            }
        }
        __syncthreads();
        f16x8 afh[4], afl[4];
#pragma unroll
        for (int rt = 0; rt < 4; rt++) {
            afh[rt] = *(const f16x8*)(Ah + (rt * 16 + l15) * LP + quad * 8);
            afl[rt] = *(const f16x8*)(Al_ + (rt * 16 + l15) * LP + quad * 8);
        }
#pragma unroll
        for (int rt = 0; rt < 4; rt++)
#pragma unroll
            for (int ct = 0; ct < 4; ct++) {
                acc[rt][ct] = __builtin_amdgcn_mfma_f32_16x16x32_f16(
                    afh[rt], bh[ct], acc[rt][ct], 0, 0, 0);
                acc[rt][ct] = __builtin_amdgcn_mfma_f32_16x16x32_f16(
                    afl[rt], bh[ct], acc[rt][ct], 0, 0, 0);
                acc[rt][ct] = __builtin_amdgcn_mfma_f32_16x16x32_f16(
                    afh[rt], bl[ct], acc[rt][ct], 0, 0, 0);
            }
        __syncthreads();
#pragma unroll
        for (int ct = 0; ct < 4; ct++) { bh[ct] = bhn[ct]; bl[ct] = bln[ct]; }
    }

    f16* dh = isQ ? Qh : Ph;
    f16* dl = isQ ? Ql : Pl;
#pragma unroll
    for (int ct = 0; ct < 4; ct++) {
        int n = wave * 64 + ct * 16 + l15;
        float bb = isQ ? 0.f : b0[colbase + n];
#pragma unroll
        for (int rt = 0; rt < 4; rt++)
#pragma unroll
            for (int reg = 0; reg < 4; reg++) {
                int gm = mbase + rt * 16 + quad * 4 + reg;
                if (gm < N_NODES) {
                    float v = acc[rt][ct][reg] + bb;
                    f16 h = (f16)v;
                    dh[(size_t)gm * H0D + colbase + n] = h;
                    dl[(size_t)gm * H0D + colbase + n] = (f16)(v - (float)h);
                }
            }
    }
}

// ---------------------------------------------------------------------------
// K3 (screen pass, DIRECT-FRAGMENT GATHER): each lane loads its own MFMA
// A-fragment rows straight from global (rows rt*16+l15, 16B slice quad*8);
// the 4 quads of an l15 jointly cover a full 64B row-slice (cacheline-
// coalesced). h1 = relu(Ph[s]+Qh[d]) in registers. NO LDS staging, ZERO
// barriers in the K-loop -> waves slip freely; compiler pipelines loads.
// lk + logits (~1e-3-class); atomicMax (lk,t) per segment.
// ---------------------------------------------------------------------------
__global__ __launch_bounds__(256, 3) void k3_f16(
        const f16* __restrict__ Pf, const f16* __restrict__ Qf,
        const f16* __restrict__ W1Bh, const float* __restrict__ b1,
        const float* __restrict__ Wlk, const float* __restrict__ blkp,
        const float* __restrict__ Wa, const float* __restrict__ ba,
        const int* __restrict__ esrc, const int* __restrict__ edst,
        unsigned long long* __restrict__ keys, float* __restrict__ lk_app,
        float* __restrict__ logits) {
    __shared__ float redA[64][5], redB[64][5], redC[64][5];
    __shared__ int s_seg[64], s_dst[64];
    const int tid = threadIdx.x;
    const int wave = tid >> 6, lane = tid & 63;
    const int quad = lane >> 4, l15 = lane & 15;
    const int tbase = blockIdx.x * 64;

    if (tid < 64) {
        int t = tbase + tid;
        int s = 0, d = -1;
        if (t < N_EDGES) { s = esrc[t]; d = edst[t]; }
        else if (t < T_TOT) { s = t - N_EDGES; }
        s_seg[tid] = s;
        s_dst[tid] = d;
    }
    __syncthreads();

    // per-lane row pointers for the 4 row-tiles this lane feeds
    const f16* prow[4];
    const f16* qrow[4];
    bool hq[4];
#pragma unroll
    for (int rt = 0; rt < 4; rt++) {
        int r = rt * 16 + l15;
        int s = s_seg[r], d = s_dst[r];
        prow[rt] = Pf + (size_t)s * H0D + quad * 8;
        hq[rt] = (d >= 0);
        qrow[rt] = Qf + (size_t)(d >= 0 ? d : 0) * H0D + quad * 8;
    }
    const f16x8 zero8 = (f16x8)(f16)0;

    f32x4 acc[4][4];
#pragma unroll
    for (int i = 0; i < 4; i++)
#pragma unroll
        for (int j = 0; j < 4; j++) acc[i][j] = (f32x4){0.f, 0.f, 0.f, 0.f};

    for (int c = 0; c < 16; c++) {
        f16x8 af[4], bf[4];
#pragma unroll
        for (int rt = 0; rt < 4; rt++) {
            f16x8 pa = *(const f16x8*)(prow[rt] + c * 32);
            f16x8 qa = hq[rt] ? *(const f16x8*)(qrow[rt] + c * 32) : zero8;
#pragma unroll
            for (int q = 0; q < 8; q++) {
                f16 s = pa[q] + qa[q];
                af[rt][q] = (s > (f16)0) ? s : (f16)0;
            }
        }
#pragma unroll
        for (int ct = 0; ct < 4; ct++)
            bf[ct] = *(const f16x8*)(W1Bh +
                ((size_t)(c * 256 + wave * 64 + ct * 16 + l15)) * 32 + quad * 8);
#pragma unroll
        for (int rt = 0; rt < 4; rt++)
#pragma unroll
            for (int ct = 0; ct < 4; ct++)
                acc[rt][ct] = __builtin_amdgcn_mfma_f32_16x16x32_f16(
                    af[rt], bf[ct], acc[rt][ct], 0, 0, 0);
    }

    float wl[4], wa0[4], wa1[4], bb[4];
#pragma unroll
    for (int ct = 0; ct < 4; ct++) {
        int n = wave * 64 + ct * 16 + l15;
        wl[ct] = Wlk[n];
        wa0[ct] = Wa[2 * n];
        wa1[ct] = Wa[2 * n + 1];
        bb[ct] = b1[n];
    }
#pragma unroll
    for (int rt = 0; rt < 4; rt++) {
#pragma unroll
        for (int reg = 0; reg < 4; reg++) {
            float plk = 0.f, p0 = 0.f, p1 = 0.f;
#pragma unroll
            for (int ct = 0; ct < 4; ct++) {
                float h = fmaxf(acc[rt][ct][reg] + bb[ct], 0.f);
                plk = fmaf(h, wl[ct], plk);
                p0 = fmaf(h, wa0[ct], p0);
                p1 = fmaf(h, wa1[ct], p1);
            }
#pragma unroll
            for (int off = 8; off >= 1; off >>= 1) {
                plk += __shfl_xor(plk, off);
                p0 += __shfl_xor(p0, off);
                p1 += __shfl_xor(p1, off);
            }
            if (l15 == 0) {
                int row = rt * 16 + quad * 4 + reg;
                redA[row][wave] = plk;
                redB[row][wave] = p0;
                redC[row][wave] = p1;
            }
        }
    }
    __syncthreads();
    if (tid < 64) {
        int t = tbase + tid;
        if (t < T_TOT) {
            float lk = redA[tid][0] + redA[tid][1] + redA[tid][2] + redA[tid][3] + blkp[0];
            float l0 = redB[tid][0] + redB[tid][1] + redB[tid][2] + redB[tid][3] + ba[0];
            float l1 = redC[tid][0] + redC[tid][1] + redC[tid][2] + redC[tid][3] + ba[1];
            lk_app[t] = lk;
            logits[2 * t] = l0;
            logits[2 * t + 1] = l1;
            unsigned long long key =
                ((unsigned long long)f2ord(lk) << 32) | (unsigned int)t;
            atomicMax(keys + s_seg[tid], key);
        }
    }
}

// ---------------------------------------------------------------------------
// K_GB: gather (a) challengers within MARGIN_LK of their segment best, plus
// the segment's approx winner ONCE per segment (seg_flag dedup);
// (b) approx winners whose logit gap < MARGIN_L.
// ---------------------------------------------------------------------------
__global__ void k_gb(const float* __restrict__ lk_app,
                     const unsigned long long* __restrict__ keys,
                     const int* __restrict__ esrc,
                     const float* __restrict__ logits,
                     int* __restrict__ seg_flag,
                     int* __restrict__ list, int* __restrict__ count) {
    int t = blockIdx.x * 256 + threadIdx.x;
    if (t < T_TOT) {
        int seg = seg_of(t, esrc);
        unsigned long long k = keys[seg];
        int tw = (int)(k & 0xFFFFFFFFull);
        if (t != tw) {
            float best = ord2f((unsigned int)(k >> 32));
            if (lk_app[t] >= best - MARGIN_LK) {
                int idx = atomicAdd(count, 1);
                if (idx < LIST_CAP) list[idx] = t;
                if (atomicExch(seg_flag + seg, 1) == 0) {
                    int idx2 = atomicAdd(count, 1);
                    if (idx2 < LIST_CAP) list[idx2] = tw;
                }
            }
        }
    }
    if (t < N_NODES) {
        int tw = (int)(keys[t] & 0xFFFFFFFFull);
        float g = fabsf(logits[2 * tw + 1] - logits[2 * tw]);
        if (g < MARGIN_L) {
            int idx = atomicAdd(count, 1);
            if (idx < LIST_CAP) list[idx] = tw;
        }
    }
}

// ---------------------------------------------------------------------------
// K_FIX2 (throughput-shaped MFMA fixup, R8 structure): 64 listed entries per
// block; A = relu((Ph+Pl)+(Qh+Ql)) rebuilt in fp32 then split; 3-term MFMA
// vs W1Ch/W1Cl (error ~2^-22). Writes exact logits[t] and (lk,t) into keys2.
// ---------------------------------------------------------------------------
__global__ __launch_bounds__(256, 2) void k_fix2(
        const f16* __restrict__ Ph, const f16* __restrict__ Pl,
        const f16* __restrict__ Qh, const f16* __restrict__ Ql,
        const f16* __restrict__ W1Ch, const f16* __restrict__ W1Cl,
        const float* __restrict__ b1, const float* __restrict__ Wlk,
        const float* __restrict__ blkp, const float* __restrict__ Wa,
        const float* __restrict__ ba, const int* __restrict__ esrc,
        const int* __restrict__ edst, const int* __restrict__ list,
        const int* __restrict__ count, unsigned long long* __restrict__ keys2,
        float* __restrict__ logits) {
    __shared__ f16 Ah[64 * LP], Al_[64 * LP];
    __shared__ float redA[64][5], redB[64][5], redC[64][5];
    __shared__ int s_seg[64], s_dst[64], s_t[64];
    const int tid = threadIdx.x;
    const int wave = tid >> 6, lane = tid & 63;
    const int quad = lane >> 4, l15 = lane & 15;
    int cnt = *count;
    if (cnt > LIST_CAP) cnt = LIST_CAP;
    const int nch = (cnt + 63) / 64;

    for (int ch = blockIdx.x; ch < nch; ch += gridDim.x) {
        if (tid < 64) {
            int li = ch * 64 + tid;
            int t = (li < cnt) ? list[li] : -1;
            int s = 0, d = -1;
            if (t >= 0 && t < T_TOT) {
                if (t < N_EDGES) { s = esrc[t]; d = edst[t]; }
                else { s = t - N_EDGES; }
            } else t = -1;
            s_t[tid] = t;
            s_seg[tid] = s;
            s_dst[tid] = d;
        }
        __syncthreads();

        const int arow = tid >> 2, akp = tid & 3;
        const int sA = s_seg[arow], dA = s_dst[arow];
        const f16* ph = Ph + (size_t)sA * H0D + akp * 8;
        const f16* pl = Pl + (size_t)sA * H0D + akp * 8;
        const f16* qh = Qh + (size_t)(dA >= 0 ? dA : 0) * H0D + akp * 8;
        const f16* ql = Ql + (size_t)(dA >= 0 ? dA : 0) * H0D + akp * 8;
        const bool hasQ = (dA >= 0);

        f32x4 acc[4][4];
#pragma unroll
        for (int i = 0; i < 4; i++)
#pragma unroll
            for (int j = 0; j < 4; j++) acc[i][j] = (f32x4){0.f, 0.f, 0.f, 0.f};

        for (int c = 0; c < 16; c++) {
            f16x8 vh = *(const f16x8*)(ph + c * 32);
            f16x8 vl = *(const f16x8*)(pl + c * 32);
            f16x8 wh, wlq;
            if (hasQ) {
                wh = *(const f16x8*)(qh + c * 32);
                wlq = *(const f16x8*)(ql + c * 32);
            }
            f16x8 hv, lv;
#pragma unroll
            for (int q = 0; q < 8; q++) {
                float v = (float)vh[q] + (float)vl[q];
                if (hasQ) v += (float)wh[q] + (float)wlq[q];
                v = fmaxf(v, 0.f);
                f16 h = (f16)v;
                hv[q] = h;
                lv[q] = (f16)(v - (float)h);
            }
            *(f16x8*)(Ah + arow * LP + akp * 8) = hv;
            *(f16x8*)(Al_ + arow * LP + akp * 8) = lv;
            f16x8 bh[4], bl[4];
#pragma unroll
            for (int ct = 0; ct < 4; ct++) {
                size_t o = ((size_t)(c * 256 + wave * 64 + ct * 16 + l15)) * 32 + quad * 8;
                bh[ct] = *(const f16x8*)(W1Ch + o);
                bl[ct] = *(const f16x8*)(W1Cl + o);
            }
            __syncthreads();
            f16x8 afh[4], afl[4];
#pragma unroll
            for (int rt = 0; rt < 4; rt++) {
                afh[rt] = *(const f16x8*)(Ah + (rt * 16 + l15) * LP + quad * 8);
                afl[rt] = *(const f16x8*)(Al_ + (rt * 16 + l15) * LP + quad * 8);
            }
#pragma unroll
            for (int rt = 0; rt < 4; rt++)
#pragma unroll
                for (int ct = 0; ct < 4; ct++) {
                    acc[rt][ct] = __builtin_amdgcn_mfma_f32_16x16x32_f16(
                        afh[rt], bh[ct], acc[rt][ct], 0, 0, 0);
                    acc[rt][ct] = __builtin_amdgcn_mfma_f32_16x16x32_f16(
                        afl[rt], bh[ct], acc[rt][ct], 0, 0, 0);
                    acc[rt][ct] = __builtin_amdgcn_mfma_f32_16x16x32_f16(
                        afh[rt], bl[ct], acc[rt][ct], 0, 0, 0);
                }
            __syncthreads();
        }

        float wl[4], wa0[4], wa1[4], bb[4];
#pragma unroll
        for (int ct = 0; ct < 4; ct++) {
            int n = wave * 64 + ct * 16 + l15;
            wl[ct] = Wlk[n];
            wa0[ct] = Wa[2 * n];
            wa1[ct] = Wa[2 * n + 1];
            bb[ct] = b1[n];
        }
#pragma unroll
        for (int rt = 0; rt < 4; rt++) {
#pragma unroll
            for (int reg = 0; reg < 4; reg++) {
                float plk = 0.f, p0 = 0.f, p1 = 0.f;
#pragma unroll
                for (int ct = 0; ct < 4; ct++) {
                    float h = fmaxf(acc[rt][ct][reg] + bb[ct], 0.f);
                    plk = fmaf(h, wl[ct], plk);
                    p0 = fmaf(h, wa0[ct], p0);
                    p1 = fmaf(h, wa1[ct], p1);
                }
#pragma unroll
                for (int off = 8; off >= 1; off >>= 1) {
                    plk += __shfl_xor(plk, off);
                    p0 += __shfl_xor(p0, off);
                    p1 += __shfl_xor(p1, off);
                }
                if (l15 == 0) {
                    int row = rt * 16 + quad * 4 + reg;
                    redA[row][wave] = plk;
                    redB[row][wave] = p0;
                    redC[row][wave] = p1;
                }
            }
        }
        __syncthreads();
        if (tid < 64) {
            int t = s_t[tid];
            if (t >= 0) {
                float lk = redA[tid][0] + redA[tid][1] + redA[tid][2] + redA[tid][3] + blkp[0];
                float l0 = redB[tid][0] + redB[tid][1] + redB[tid][2] + redB[tid][3] + ba[0];
                float l1 = redC[tid][0] + redC[tid][1] + redC[tid][2] + redC[tid][3] + ba[1];
                logits[2 * t] = l0;
                logits[2 * t + 1] = l1;
                unsigned long long key =
                    ((unsigned long long)f2ord(lk) << 32) | (unsigned int)t;
                atomicMax(keys2 + s_seg[tid], key);
            }
        }
        __syncthreads();
    }
}

// ---------------------------------------------------------------------------
// K4: winner per node (keys2 if exact candidates exist, else approx keys);
// at-bit from logits; last-writer claim (+1 coded).
// ---------------------------------------------------------------------------
__global__ void k4_select(const unsigned long long* __restrict__ keys,
                          const unsigned long long* __restrict__ keys2,
                          const int* __restrict__ edst,
                          const float* __restrict__ logits,
                          int* __restrict__ chosen_arr,
                          int* __restrict__ tgt_writer) {
    int i = blockIdx.x * 256 + threadIdx.x;
    if (i >= N_NODES) return;
    unsigned long long key = keys[i];
    unsigned long long k2v = keys2[i];
    if (k2v != 0ull) key = k2v;
    int t = (int)(key & 0xFFFFFFFFull);
    int chosen = (t < N_EDGES) ? edst[t] : -1;
    float lg0 = logits[2 * t], lg1 = logits[2 * t + 1];
    int at1 = (lg1 > lg0) ? 1 : 0;   // argmax: tie -> index 0
    int c = (chosen >= 0 && at1) ? chosen : -1;
    chosen_arr[i] = c;
    if (c >= 0) atomicMax(tgt_writer + c, i + 1);   // last-write-wins: max i
}

// ---------------------------------------------------------------------------
// K5: winning writers update rows: out[c] = relu(0.5*(Z[i] + Z[c]))
// ---------------------------------------------------------------------------
__global__ void k5_update(const int* __restrict__ chosen_arr,
                          const int* __restrict__ tgt_writer,
                          const float* __restrict__ Z,
                          float* __restrict__ out) {
    int i = blockIdx.x;
    int c = chosen_arr[i];
    if (c < 0 || tgt_writer[c] != i + 1) return;
    int n = threadIdx.x;
    float z = 0.5f * (Z[(size_t)i * E_DIM + n] + Z[(size_t)c * E_DIM + n]);
    out[(size_t)c * E_DIM + n] = fmaxf(z, 0.f);
}

// ---------------------------------------------------------------------------
extern "C" void kernel_launch(void* const* d_in, const int* in_sizes, int n_in,
                              void* d_out, int out_size, void* d_ws,
                              size_t ws_size, hipStream_t stream) {
    const float* feat = (const float*)d_in[0];
    const float* We   = (const float*)d_in[1];
    const float* be   = (const float*)d_in[2];
    const float* W0   = (const float*)d_in[3];
    const float* b0   = (const float*)d_in[4];
    const float* W1   = (const float*)d_in[5];
    const float* b1   = (const float*)d_in[6];
    const float* Wlk  = (const float*)d_in[7];
    const float* blkp = (const float*)d_in[8];
    const float* Wa   = (const float*)d_in[9];
    const float* ba   = (const float*)d_in[10];
    const int* esrc   = (const int*)d_in[11];
    const int* edst   = (const int*)d_in[12];
    float* out = (float*)d_out;

    char* ws = (char*)d_ws;
    size_t off = 0;
    float* Z  = (float*)(ws + off); off += (size_t)N_NODES * E_DIM * 4;
    f16* Ph   = (f16*)(ws + off);   off += (size_t)N_NODES * H0D * 2;
    f16* Pl   = (f16*)(ws + off);   off += (size_t)N_NODES * H0D * 2;
    f16* Qh   = (f16*)(ws + off);   off += (size_t)N_NODES * H0D * 2;
    f16* Ql   = (f16*)(ws + off);   off += (size_t)N_NODES * H0D * 2;
    // ---- contiguous zero-init region ----
    char* zero_base = ws + off;
    unsigned long long* keys  = (unsigned long long*)(ws + off); off += N_NODES * 8;
    unsigned long long* keys2 = (unsigned long long*)(ws + off); off += N_NODES * 8;
    int* tgt_writer = (int*)(ws + off); off += N_NODES * 4;   // +1 encoding, 0 = none
    int* seg_flag   = (int*)(ws + off); off += N_NODES * 4;
    int* count      = (int*)(ws + off); off += 128;
    size_t zero_bytes = (size_t)((ws + off) - zero_base);
    // -------------------------------------
    float* logits = (float*)(ws + off); off += (size_t)T_TOT * 2 * 4;
    float* lk_app = (float*)(ws + off); off += (size_t)T_TOT * 4;
    int* list     = (int*)(ws + off); off += (size_t)LIST_CAP * 4;
    int* chosen_arr = (int*)(ws + off); off += N_NODES * 4;
    f16* WeC_h = (f16*)(ws + off); off += (size_t)16 * 256 * 32 * 2;
    f16* WeC_l = (f16*)(ws + off); off += (size_t)16 * 256 * 32 * 2;
    f16* W1C_h = (f16*)(ws + off); off += (size_t)16 * 256 * 32 * 2;
    f16* W1C_l = (f16*)(ws + off); off += (size_t)16 * 256 * 32 * 2;
    f16* W0C_h = (f16*)(ws + off); off += (size_t)32 * 256 * 32 * 2;
    f16* W0C_l = (f16*)(ws + off); off += (size_t)32 * 256 * 32 * 2;

    hipMemsetAsync(zero_base, 0, zero_bytes, stream);

    k_prep_all<<<dim3(64), 256, 0, stream>>>(
        We, W1, W0, WeC_h, WeC_l, W1C_h, W1C_l, W0C_h, W0C_l);
    k1_split<<<dim3((N_NODES + 31) / 32), 256, 0, stream>>>(
        feat, WeC_h, WeC_l, be, Z, out);
    k2_split<<<dim3((N_NODES + 63) / 64, 4), 256, 0, stream>>>(
        out, W0C_h, W0C_l, b0, Ph, Pl, Qh, Ql);
    k3_f16<<<dim3((T_TOT + 63) / 64), 256, 0, stream>>>(
        Ph, Qh, W1C_h, b1, Wlk, blkp, Wa, ba, esrc, edst,
        keys, lk_app, logits);
    k_gb<<<dim3((T_TOT + 255) / 256), 256, 0, stream>>>(
        lk_app, keys, esrc, logits, seg_flag, list, count);
    k_fix2<<<dim3(FIX_GRID), 256, 0, stream>>>(
        Ph, Pl, Qh, Ql, W1C_h, W1C_l, b1, Wlk, blkp, Wa, ba,
        esrc, edst, list, count, keys2, logits);
    k4_select<<<dim3((N_NODES + 255) / 256), 256, 0, stream>>>(
        keys, keys2, edst, logits, chosen_arr, tgt_writer);
    k5_update<<<dim3(N_NODES), 256, 0, stream>>>(chosen_arr, tgt_writer, Z, out);
}

// Round 13
// 273.740 us; speedup vs baseline: 1.4626x; 1.4626x over previous
//
#include <hip/hip_runtime.h>
#include <stdint.h>

#define N_NODES 10000
#define F_IN    512
#define E_DIM   256
#define H0D     512
#define H1D     256
#define N_EDGES 160000
#define T_TOT   (N_EDGES + N_NODES)   // 170000

#define MARGIN_LK 4e-3f
#define MARGIN_L  4e-3f
#define LIST_CAP 60000
#define FIX_GRID 512
#define LP 40                       // padded LDS row stride in f16 (80B)

typedef _Float16 f16;
typedef __attribute__((ext_vector_type(8))) _Float16 f16x8;
typedef __attribute__((ext_vector_type(4))) _Float16 f16x4;
typedef __attribute__((ext_vector_type(4))) float f32x4;

// monotone map fp32 -> uint32 (order-preserving)
__device__ __forceinline__ unsigned int f2ord(float f) {
    unsigned int u = __float_as_uint(f);
    return (u & 0x80000000u) ? ~u : (u | 0x80000000u);
}
__device__ __forceinline__ float ord2f(unsigned int o) {
    unsigned int u = (o & 0x80000000u) ? (o & 0x7fffffffu) : ~o;
    return __uint_as_float(u);
}

__device__ __forceinline__ int seg_of(int t, const int* esrc) {
    return (t < N_EDGES) ? esrc[t] : t - N_EDGES;
}

// ---------------------------------------------------------------------------
// K_PREP_ALL: weight matrices -> chunked n-major split-f16 images.
// blocks 0-15: We; 16-31: W1; 32-63: W0 (4 groups x 8 chunks).
// ---------------------------------------------------------------------------
__global__ void k_prep_all(const float* __restrict__ We,
                           const float* __restrict__ W1,
                           const float* __restrict__ W0,
                           f16* __restrict__ WeC_h, f16* __restrict__ WeC_l,
                           f16* __restrict__ W1C_h, f16* __restrict__ W1C_l,
                           f16* __restrict__ W0C_h, f16* __restrict__ W0C_l) {
    int b = blockIdx.x;
    int n = threadIdx.x;
    const float* W;
    int ld, rowoff, colbase, c;
    f16 *dh_base, *dl_base;
    if (b < 16) {
        W = We; ld = E_DIM; rowoff = 0; colbase = 0; c = b;
        dh_base = WeC_h; dl_base = WeC_l;
    } else if (b < 32) {
        W = W1; ld = H1D; rowoff = 0; colbase = 0; c = b - 16;
        dh_base = W1C_h; dl_base = W1C_l;
    } else {
        int g = (b - 32) >> 3; c = (b - 32) & 7;
        rowoff = (g >= 2) ? 256 : 0; colbase = (g & 1) * 256;
        W = W0; ld = H0D;
        dh_base = W0C_h + (size_t)g * 8 * 256 * 32;
        dl_base = W0C_l + (size_t)g * 8 * 256 * 32;
    }
    f16* dh = dh_base + ((size_t)c * 256 + n) * 32;
    f16* dl = dl_base + ((size_t)c * 256 + n) * 32;
    const float* src = W + (size_t)(rowoff + c * 32) * ld + colbase + n;
#pragma unroll
    for (int kk = 0; kk < 32; kk++) {
        float w = src[(size_t)kk * ld];
        f16 h = (f16)w;
        f16 l = (f16)(w - (float)h);
        dh[kk] = h;
        dl[kk] = l;
    }
}

// ---------------------------------------------------------------------------
// K1: Z = feature @ We + be (3-term split-f16, fp32-class);  out = relu(Z)
// 32-row tiles, register-B, A-only LDS.
// ---------------------------------------------------------------------------
__global__ __launch_bounds__(256, 2) void k1_split(
        const float* __restrict__ feat, const f16* __restrict__ Bh_g,
        const f16* __restrict__ Bl_g, const float* __restrict__ be,
        float* __restrict__ Z, float* __restrict__ out) {
    __shared__ f16 Ah[32 * LP], Al_[32 * LP];
    const int tid = threadIdx.x;
    const int wave = tid >> 6, lane = tid & 63;
    const int quad = lane >> 4, l15 = lane & 15;
    const int mbase = blockIdx.x * 32;
    const int arow = tid >> 3, apos = tid & 7;
    const int gm_a = mbase + arow;
    const float* Arow = feat + (size_t)gm_a * F_IN + apos * 4;
    const bool rowok = (gm_a < N_NODES);

    f32x4 acc[2][4];
#pragma unroll
    for (int i = 0; i < 2; i++)
#pragma unroll
        for (int j = 0; j < 4; j++) acc[i][j] = (f32x4){0.f, 0.f, 0.f, 0.f};

    f16x8 bh[4], bl[4], bhn[4], bln[4];
#pragma unroll
    for (int ct = 0; ct < 4; ct++) {
        size_t o = ((size_t)(wave * 64 + ct * 16 + l15)) * 32 + quad * 8;
        bh[ct] = *(const f16x8*)(Bh_g + o);
        bl[ct] = *(const f16x8*)(Bl_g + o);
    }
    float4 a = rowok ? *(const float4*)(Arow) : make_float4(0.f, 0.f, 0.f, 0.f);

    for (int c = 0; c < 16; c++) {
        f16x4 hv, lv;
        float av[4] = {a.x, a.y, a.z, a.w};
#pragma unroll
        for (int q = 0; q < 4; q++) {
            f16 h = (f16)av[q];
            hv[q] = h;
            lv[q] = (f16)(av[q] - (float)h);
        }
        *(f16x4*)(Ah + arow * LP + apos * 4) = hv;
        *(f16x4*)(Al_ + arow * LP + apos * 4) = lv;
        if (c + 1 < 16) {
            a = rowok ? *(const float4*)(Arow + (c + 1) * 32)
                      : make_float4(0.f, 0.f, 0.f, 0.f);
#pragma unroll
            for (int ct = 0; ct < 4; ct++) {
                size_t o = ((size_t)((c + 1) * 256 + wave * 64 + ct * 16 + l15)) * 32 + quad * 8;
                bhn[ct] = *(const f16x8*)(Bh_g + o);
                bln[ct] = *(const f16x8*)(Bl_g + o);
            }
        }
        __syncthreads();
        f16x8 afh[2], afl[2];
#pragma unroll
        for (int rt = 0; rt < 2; rt++) {
            afh[rt] = *(const f16x8*)(Ah + (rt * 16 + l15) * LP + quad * 8);
            afl[rt] = *(const f16x8*)(Al_ + (rt * 16 + l15) * LP + quad * 8);
        }
#pragma unroll
        for (int rt = 0; rt < 2; rt++)
#pragma unroll
            for (int ct = 0; ct < 4; ct++) {
                acc[rt][ct] = __builtin_amdgcn_mfma_f32_16x16x32_f16(
                    afh[rt], bh[ct], acc[rt][ct], 0, 0, 0);
                acc[rt][ct] = __builtin_amdgcn_mfma_f32_16x16x32_f16(
                    afl[rt], bh[ct], acc[rt][ct], 0, 0, 0);
                acc[rt][ct] = __builtin_amdgcn_mfma_f32_16x16x32_f16(
                    afh[rt], bl[ct], acc[rt][ct], 0, 0, 0);
            }
        __syncthreads();
#pragma unroll
        for (int ct = 0; ct < 4; ct++) { bh[ct] = bhn[ct]; bl[ct] = bln[ct]; }
    }

#pragma unroll
    for (int ct = 0; ct < 4; ct++) {
        int n = wave * 64 + ct * 16 + l15;
        float bb = be[n];
#pragma unroll
        for (int rt = 0; rt < 2; rt++)
#pragma unroll
            for (int reg = 0; reg < 4; reg++) {
                int gm = mbase + rt * 16 + quad * 4 + reg;
                if (gm < N_NODES) {
                    float z = acc[rt][ct][reg] + bb;
                    Z[(size_t)gm * E_DIM + n] = z;
                    out[(size_t)gm * E_DIM + n] = fmaxf(z, 0.f);
                }
            }
    }
}

// ---------------------------------------------------------------------------
// K2: P = emb @ W0[0:256,:] + b0 ; Q = emb @ W0[256:512,:]  (3-term exact)
// Stores SPLIT f16: Ph/Pl and Qh/Ql (Ph+Pl reconstructs fp32 P to ~2^-22).
// ---------------------------------------------------------------------------
__global__ __launch_bounds__(256, 3) void k2_split(
        const float* __restrict__ emb, const f16* __restrict__ W0Ch,
        const f16* __restrict__ W0Cl, const float* __restrict__ b0,
        f16* __restrict__ Ph, f16* __restrict__ Pl,
        f16* __restrict__ Qh, f16* __restrict__ Ql) {
    __shared__ f16 Ah[64 * LP], Al_[64 * LP];
    const int tid = threadIdx.x;
    const int wave = tid >> 6, lane = tid & 63;
    const int quad = lane >> 4, l15 = lane & 15;
    const int mbase = blockIdx.x * 64;
    const int g = blockIdx.y;
    const int isQ = (g >= 2);
    const int colbase = (g & 1) * 256;
    const int arow = tid >> 2, akp = tid & 3;
    const int gm_a = mbase + arow;
    const float* Arow = emb + (size_t)gm_a * E_DIM + akp * 8;
    const bool rowok = (gm_a < N_NODES);
    const f16* Bh_g = W0Ch + (size_t)g * 8 * 256 * 32;
    const f16* Bl_g = W0Cl + (size_t)g * 8 * 256 * 32;

    f32x4 acc[4][4];
#pragma unroll
    for (int i = 0; i < 4; i++)
#pragma unroll
        for (int j = 0; j < 4; j++) acc[i][j] = (f32x4){0.f, 0.f, 0.f, 0.f};

    f16x8 bh[4], bl[4], bhn[4], bln[4];
#pragma unroll
    for (int ct = 0; ct < 4; ct++) {
        size_t o = ((size_t)(wave * 64 + ct * 16 + l15)) * 32 + quad * 8;
        bh[ct] = *(const f16x8*)(Bh_g + o);
        bl[ct] = *(const f16x8*)(Bl_g + o);
    }
    float4 a0 = make_float4(0.f, 0.f, 0.f, 0.f), a1 = a0;
    if (rowok) { a0 = *(const float4*)(Arow); a1 = *(const float4*)(Arow + 4); }

    for (int c = 0; c < 8; c++) {
        f16x8 hv, lv;
        float av[8] = {a0.x, a0.y, a0.z, a0.w, a1.x, a1.y, a1.z, a1.w};
#pragma unroll
        for (int q = 0; q < 8; q++) {
            f16 h = (f16)av[q];
            hv[q] = h;
            lv[q] = (f16)(av[q] - (float)h);
        }
        *(f16x8*)(Ah + arow * LP + akp * 8) = hv;
        *(f16x8*)(Al_ + arow * LP + akp * 8) = lv;
        if (c + 1 < 8) {
            if (rowok) {
                a0 = *(const float4*)(Arow + (c + 1) * 32);
                a1 = *(const float4*)(Arow + (c + 1) * 32 + 4);
            }
#pragma unroll
            for (int ct = 0; ct < 4; ct++) {
                size_t o = ((size_t)((c + 1) * 256 + wave * 64 + ct * 16 + l15)) * 32 + quad * 8;
                bhn[ct] = *(const f16x8*)(Bh_g + o);
                bln[ct] = *(const f16x8*)(Bl_g + o);
            }
        }
        __syncthreads();
        f16x8 afh[4], afl[4];
#pragma unroll
        for (int rt = 0; rt < 4; rt++) {
            afh[rt] = *(const f16x8*)(Ah + (rt * 16 + l15) * LP + quad * 8);
            afl[rt] = *(const f16x8*)(Al_ + (rt * 16 + l15) * LP + quad * 8);
        }
#pragma unroll
        for (int rt = 0; rt < 4; rt++)
#pragma unroll
            for (int ct = 0; ct < 4; ct++) {
                acc[rt][ct] = __builtin_amdgcn_mfma_f32_16x16x32_f16(
                    afh[rt], bh[ct], acc[rt][ct], 0, 0, 0);
                acc[rt][ct] = __builtin_amdgcn_mfma_f32_16x16x32_f16(
                    afl[rt], bh[ct], acc[rt][ct], 0, 0, 0);
                acc[rt][ct] = __builtin_amdgcn_mfma_f32_16x16x32_f16(
                    afh[rt], bl[ct], acc[rt][ct], 0, 0, 0);
            }
        __syncthreads();
#pragma unroll
        for (int ct = 0; ct < 4; ct++) { bh[ct] = bhn[ct]; bl[ct] = bln[ct]; }
    }

    f16* dh = isQ ? Qh : Ph;
    f16* dl = isQ ? Ql : Pl;
#pragma unroll
    for (int ct = 0; ct < 4; ct++) {
        int n = wave * 64 + ct * 16 + l15;
        float bb = isQ ? 0.f : b0[colbase + n];
#pragma unroll
        for (int rt = 0; rt < 4; rt++)
#pragma unroll
            for (int reg = 0; reg < 4; reg++) {
                int gm = mbase + rt * 16 + quad * 4 + reg;
                if (gm < N_NODES) {
                    float v = acc[rt][ct][reg] + bb;
                    f16 h = (f16)v;
                    dh[(size_t)gm * H0D + colbase + n] = h;
                    dl[(size_t)gm * H0D + colbase + n] = (f16)(v - (float)h);
                }
            }
    }
}

// ---------------------------------------------------------------------------
// K3 (screen pass, 1-term, register-B, A-only LDS — the R8 empirical optimum):
// h1 = relu(Ph[s]+Qh[d]); h = relu(h1@W1h+b1); lk + logits (~1e-3-class).
// atomicMax (lk,t) per segment.
// ---------------------------------------------------------------------------
__global__ __launch_bounds__(256, 3) void k3_f16(
        const f16* __restrict__ Pf, const f16* __restrict__ Qf,
        const f16* __restrict__ W1Bh, const float* __restrict__ b1,
        const float* __restrict__ Wlk, const float* __restrict__ blkp,
        const float* __restrict__ Wa, const float* __restrict__ ba,
        const int* __restrict__ esrc, const int* __restrict__ edst,
        unsigned long long* __restrict__ keys, float* __restrict__ lk_app,
        float* __restrict__ logits) {
    __shared__ f16 Ah[64 * LP];
    __shared__ float redA[64][5], redB[64][5], redC[64][5];
    __shared__ int s_seg[64], s_dst[64];
    const int tid = threadIdx.x;
    const int wave = tid >> 6, lane = tid & 63;
    const int quad = lane >> 4, l15 = lane & 15;
    const int tbase = blockIdx.x * 64;

    if (tid < 64) {
        int t = tbase + tid;
        int s = 0, d = -1;
        if (t < N_EDGES) { s = esrc[t]; d = edst[t]; }
        else if (t < T_TOT) { s = t - N_EDGES; }
        s_seg[tid] = s;
        s_dst[tid] = d;
    }
    __syncthreads();

    const int arow = tid >> 2, akp = tid & 3;
    const int sA = s_seg[arow], dA = s_dst[arow];
    const f16* Prow = Pf + (size_t)sA * H0D + akp * 8;
    const f16* Qrow = Qf + (size_t)(dA >= 0 ? dA : 0) * H0D + akp * 8;
    const bool hasQ = (dA >= 0);
    const f16x8 zero8 = (f16x8)(f16)0;

    f32x4 acc[4][4];
#pragma unroll
    for (int i = 0; i < 4; i++)
#pragma unroll
        for (int j = 0; j < 4; j++) acc[i][j] = (f32x4){0.f, 0.f, 0.f, 0.f};

    f16x8 pa = *(const f16x8*)(Prow);
    f16x8 qa = hasQ ? *(const f16x8*)(Qrow) : zero8;
    f16x8 bf[4], bfn[4];
#pragma unroll
    for (int ct = 0; ct < 4; ct++)
        bf[ct] = *(const f16x8*)(W1Bh + ((size_t)(wave * 64 + ct * 16 + l15)) * 32 + quad * 8);

    for (int c = 0; c < 16; c++) {
        f16x8 hv;
#pragma unroll
        for (int q = 0; q < 8; q++) {
            f16 s = pa[q] + qa[q];
            hv[q] = (s > (f16)0) ? s : (f16)0;
        }
        *(f16x8*)(Ah + arow * LP + akp * 8) = hv;
        if (c + 1 < 16) {
            pa = *(const f16x8*)(Prow + (c + 1) * 32);
            qa = hasQ ? *(const f16x8*)(Qrow + (c + 1) * 32) : zero8;
#pragma unroll
            for (int ct = 0; ct < 4; ct++)
                bfn[ct] = *(const f16x8*)(W1Bh +
                    ((size_t)((c + 1) * 256 + wave * 64 + ct * 16 + l15)) * 32 + quad * 8);
        }
        __syncthreads();
        f16x8 af[4];
#pragma unroll
        for (int rt = 0; rt < 4; rt++)
            af[rt] = *(const f16x8*)(Ah + (rt * 16 + l15) * LP + quad * 8);
#pragma unroll
        for (int rt = 0; rt < 4; rt++)
#pragma unroll
            for (int ct = 0; ct < 4; ct++)
                acc[rt][ct] = __builtin_amdgcn_mfma_f32_16x16x32_f16(
                    af[rt], bf[ct], acc[rt][ct], 0, 0, 0);
        __syncthreads();
#pragma unroll
        for (int ct = 0; ct < 4; ct++) bf[ct] = bfn[ct];
    }

    float wl[4], wa0[4], wa1[4], bb[4];
#pragma unroll
    for (int ct = 0; ct < 4; ct++) {
        int n = wave * 64 + ct * 16 + l15;
        wl[ct] = Wlk[n];
        wa0[ct] = Wa[2 * n];
        wa1[ct] = Wa[2 * n + 1];
        bb[ct] = b1[n];
    }
#pragma unroll
    for (int rt = 0; rt < 4; rt++) {
#pragma unroll
        for (int reg = 0; reg < 4; reg++) {
            float plk = 0.f, p0 = 0.f, p1 = 0.f;
#pragma unroll
            for (int ct = 0; ct < 4; ct++) {
                float h = fmaxf(acc[rt][ct][reg] + bb[ct], 0.f);
                plk = fmaf(h, wl[ct], plk);
                p0 = fmaf(h, wa0[ct], p0);
                p1 = fmaf(h, wa1[ct], p1);
            }
#pragma unroll
            for (int off = 8; off >= 1; off >>= 1) {
                plk += __shfl_xor(plk, off);
                p0 += __shfl_xor(p0, off);
                p1 += __shfl_xor(p1, off);
            }
            if (l15 == 0) {
                int row = rt * 16 + quad * 4 + reg;
                redA[row][wave] = plk;
                redB[row][wave] = p0;
                redC[row][wave] = p1;
            }
        }
    }
    __syncthreads();
    if (tid < 64) {
        int t = tbase + tid;
        if (t < T_TOT) {
            float lk = redA[tid][0] + redA[tid][1] + redA[tid][2] + redA[tid][3] + blkp[0];
            float l0 = redB[tid][0] + redB[tid][1] + redB[tid][2] + redB[tid][3] + ba[0];
            float l1 = redC[tid][0] + redC[tid][1] + redC[tid][2] + redC[tid][3] + ba[1];
            lk_app[t] = lk;
            logits[2 * t] = l0;
            logits[2 * t + 1] = l1;
            unsigned long long key =
                ((unsigned long long)f2ord(lk) << 32) | (unsigned int)t;
            atomicMax(keys + s_seg[tid], key);
        }
    }
}

// ---------------------------------------------------------------------------
// K_GB: gather (a) challengers within MARGIN_LK of their segment best, plus
// the segment's approx winner ONCE per segment (seg_flag dedup);
// (b) approx winners whose logit gap < MARGIN_L.
// ---------------------------------------------------------------------------
__global__ void k_gb(const float* __restrict__ lk_app,
                     const unsigned long long* __restrict__ keys,
                     const int* __restrict__ esrc,
                     const float* __restrict__ logits,
                     int* __restrict__ seg_flag,
                     int* __restrict__ list, int* __restrict__ count) {
    int t = blockIdx.x * 256 + threadIdx.x;
    if (t < T_TOT) {
        int seg = seg_of(t, esrc);
        unsigned long long k = keys[seg];
        int tw = (int)(k & 0xFFFFFFFFull);
        if (t != tw) {
            float best = ord2f((unsigned int)(k >> 32));
            if (lk_app[t] >= best - MARGIN_LK) {
                int idx = atomicAdd(count, 1);
                if (idx < LIST_CAP) list[idx] = t;
                if (atomicExch(seg_flag + seg, 1) == 0) {
                    int idx2 = atomicAdd(count, 1);
                    if (idx2 < LIST_CAP) list[idx2] = tw;
                }
            }
        }
    }
    if (t < N_NODES) {
        int tw = (int)(keys[t] & 0xFFFFFFFFull);
        float g = fabsf(logits[2 * tw + 1] - logits[2 * tw]);
        if (g < MARGIN_L) {
            int idx = atomicAdd(count, 1);
            if (idx < LIST_CAP) list[idx] = tw;
        }
    }
}

// ---------------------------------------------------------------------------
// K_FIX2 (throughput-shaped MFMA fixup, R8 structure): 64 listed entries per
// block; A = relu((Ph+Pl)+(Qh+Ql)) rebuilt in fp32 then split; 3-term MFMA
// vs W1Ch/W1Cl (error ~2^-22). Writes exact logits[t] and (lk,t) into keys2.
// ---------------------------------------------------------------------------
__global__ __launch_bounds__(256, 2) void k_fix2(
        const f16* __restrict__ Ph, const f16* __restrict__ Pl,
        const f16* __restrict__ Qh, const f16* __restrict__ Ql,
        const f16* __restrict__ W1Ch, const f16* __restrict__ W1Cl,
        const float* __restrict__ b1, const float* __restrict__ Wlk,
        const float* __restrict__ blkp, const float* __restrict__ Wa,
        const float* __restrict__ ba, const int* __restrict__ esrc,
        const int* __restrict__ edst, const int* __restrict__ list,
        const int* __restrict__ count, unsigned long long* __restrict__ keys2,
        float* __restrict__ logits) {
    __shared__ f16 Ah[64 * LP], Al_[64 * LP];
    __shared__ float redA[64][5], redB[64][5], redC[64][5];
    __shared__ int s_seg[64], s_dst[64], s_t[64];
    const int tid = threadIdx.x;
    const int wave = tid >> 6, lane = tid & 63;
    const int quad = lane >> 4, l15 = lane & 15;
    int cnt = *count;
    if (cnt > LIST_CAP) cnt = LIST_CAP;
    const int nch = (cnt + 63) / 64;

    for (int ch = blockIdx.x; ch < nch; ch += gridDim.x) {
        if (tid < 64) {
            int li = ch * 64 + tid;
            int t = (li < cnt) ? list[li] : -1;
            int s = 0, d = -1;
            if (t >= 0 && t < T_TOT) {
                if (t < N_EDGES) { s = esrc[t]; d = edst[t]; }
                else { s = t - N_EDGES; }
            } else t = -1;
            s_t[tid] = t;
            s_seg[tid] = s;
            s_dst[tid] = d;
        }
        __syncthreads();

        const int arow = tid >> 2, akp = tid & 3;
        const int sA = s_seg[arow], dA = s_dst[arow];
        const f16* ph = Ph + (size_t)sA * H0D + akp * 8;
        const f16* pl = Pl + (size_t)sA * H0D + akp * 8;
        const f16* qh = Qh + (size_t)(dA >= 0 ? dA : 0) * H0D + akp * 8;
        const f16* ql = Ql + (size_t)(dA >= 0 ? dA : 0) * H0D + akp * 8;
        const bool hasQ = (dA >= 0);

        f32x4 acc[4][4];
#pragma unroll
        for (int i = 0; i < 4; i++)
#pragma unroll
            for (int j = 0; j < 4; j++) acc[i][j] = (f32x4){0.f, 0.f, 0.f, 0.f};

        for (int c = 0; c < 16; c++) {
            f16x8 vh = *(const f16x8*)(ph + c * 32);
            f16x8 vl = *(const f16x8*)(pl + c * 32);
            f16x8 wh, wlq;
            if (hasQ) {
                wh = *(const f16x8*)(qh + c * 32);
                wlq = *(const f16x8*)(ql + c * 32);
            }
            f16x8 hv, lv;
#pragma unroll
            for (int q = 0; q < 8; q++) {
                float v = (float)vh[q] + (float)vl[q];
                if (hasQ) v += (float)wh[q] + (float)wlq[q];
                v = fmaxf(v, 0.f);
                f16 h = (f16)v;
                hv[q] = h;
                lv[q] = (f16)(v - (float)h);
            }
            *(f16x8*)(Ah + arow * LP + akp * 8) = hv;
            *(f16x8*)(Al_ + arow * LP + akp * 8) = lv;
            f16x8 bh[4], bl[4];
#pragma unroll
            for (int ct = 0; ct < 4; ct++) {
                size_t o = ((size_t)(c * 256 + wave * 64 + ct * 16 + l15)) * 32 + quad * 8;
                bh[ct] = *(const f16x8*)(W1Ch + o);
                bl[ct] = *(const f16x8*)(W1Cl + o);
            }
            __syncthreads();
            f16x8 afh[4], afl[4];
#pragma unroll
            for (int rt = 0; rt < 4; rt++) {
                afh[rt] = *(const f16x8*)(Ah + (rt * 16 + l15) * LP + quad * 8);
                afl[rt] = *(const f16x8*)(Al_ + (rt * 16 + l15) * LP + quad * 8);
            }
#pragma unroll
            for (int rt = 0; rt < 4; rt++)
#pragma unroll
                for (int ct = 0; ct < 4; ct++) {
                    acc[rt][ct] = __builtin_amdgcn_mfma_f32_16x16x32_f16(
                        afh[rt], bh[ct], acc[rt][ct], 0, 0, 0);
                    acc[rt][ct] = __builtin_amdgcn_mfma_f32_16x16x32_f16(
                        afl[rt], bh[ct], acc[rt][ct], 0, 0, 0);
                    acc[rt][ct] = __builtin_amdgcn_mfma_f32_16x16x32_f16(
                        afh[rt], bl[ct], acc[rt][ct], 0, 0, 0);
                }
            __syncthreads();
        }

        float wl[4], wa0[4], wa1[4], bb[4];
#pragma unroll
        for (int ct = 0; ct < 4; ct++) {
            int n = wave * 64 + ct * 16 + l15;
            wl[ct] = Wlk[n];
            wa0[ct] = Wa[2 * n];
            wa1[ct] = Wa[2 * n + 1];
            bb[ct] = b1[n];
        }
#pragma unroll
        for (int rt = 0; rt < 4; rt++) {
#pragma unroll
            for (int reg = 0; reg < 4; reg++) {
                float plk = 0.f, p0 = 0.f, p1 = 0.f;
#pragma unroll
                for (int ct = 0; ct < 4; ct++) {
                    float h = fmaxf(acc[rt][ct][reg] + bb[ct], 0.f);
                    plk = fmaf(h, wl[ct], plk);
                    p0 = fmaf(h, wa0[ct], p0);
                    p1 = fmaf(h, wa1[ct], p1);
                }
#pragma unroll
                for (int off = 8; off >= 1; off >>= 1) {
                    plk += __shfl_xor(plk, off);
                    p0 += __shfl_xor(p0, off);
                    p1 += __shfl_xor(p1, off);
                }
                if (l15 == 0) {
                    int row = rt * 16 + quad * 4 + reg;
                    redA[row][wave] = plk;
                    redB[row][wave] = p0;
                    redC[row][wave] = p1;
                }
            }
        }
        __syncthreads();
        if (tid < 64) {
            int t = s_t[tid];
            if (t >= 0) {
                float lk = redA[tid][0] + redA[tid][1] + redA[tid][2] + redA[tid][3] + blkp[0];
                float l0 = redB[tid][0] + redB[tid][1] + redB[tid][2] + redB[tid][3] + ba[0];
                float l1 = redC[tid][0] + redC[tid][1] + redC[tid][2] + redC[tid][3] + ba[1];
                logits[2 * t] = l0;
                logits[2 * t + 1] = l1;
                unsigned long long key =
                    ((unsigned long long)f2ord(lk) << 32) | (unsigned int)t;
                atomicMax(keys2 + s_seg[tid], key);
            }
        }
        __syncthreads();
    }
}

// ---------------------------------------------------------------------------
// K4: winner per node (keys2 if exact candidates exist, else approx keys);
// at-bit from logits; last-writer claim (+1 coded).
// ---------------------------------------------------------------------------
__global__ void k4_select(const unsigned long long* __restrict__ keys,
                          const unsigned long long* __restrict__ keys2,
                          const int* __restrict__ edst,
                          const float* __restrict__ logits,
                          int* __restrict__ chosen_arr,
                          int* __restrict__ tgt_writer) {
    int i = blockIdx.x * 256 + threadIdx.x;
    if (i >= N_NODES) return;
    unsigned long long key = keys[i];
    unsigned long long k2v = keys2[i];
    if (k2v != 0ull) key = k2v;
    int t = (int)(key & 0xFFFFFFFFull);
    int chosen = (t < N_EDGES) ? edst[t] : -1;
    float lg0 = logits[2 * t], lg1 = logits[2 * t + 1];
    int at1 = (lg1 > lg0) ? 1 : 0;   // argmax: tie -> index 0
    int c = (chosen >= 0 && at1) ? chosen : -1;
    chosen_arr[i] = c;
    if (c >= 0) atomicMax(tgt_writer + c, i + 1);   // last-write-wins: max i
}

// ---------------------------------------------------------------------------
// K5: winning writers update rows: out[c] = relu(0.5*(Z[i] + Z[c]))
// ---------------------------------------------------------------------------
__global__ void k5_update(const int* __restrict__ chosen_arr,
                          const int* __restrict__ tgt_writer,
                          const float* __restrict__ Z,
                          float* __restrict__ out) {
    int i = blockIdx.x;
    int c = chosen_arr[i];
    if (c < 0 || tgt_writer[c] != i + 1) return;
    int n = threadIdx.x;
    float z = 0.5f * (Z[(size_t)i * E_DIM + n] + Z[(size_t)c * E_DIM + n]);
    out[(size_t)c * E_DIM + n] = fmaxf(z, 0.f);
}

// ---------------------------------------------------------------------------
extern "C" void kernel_launch(void* const* d_in, const int* in_sizes, int n_in,
                              void* d_out, int out_size, void* d_ws,
                              size_t ws_size, hipStream_t stream) {
    const float* feat = (const float*)d_in[0];
    const float* We   = (const float*)d_in[1];
    const float* be   = (const float*)d_in[2];
    const float* W0   = (const float*)d_in[3];
    const float* b0   = (const float*)d_in[4];
    const float* W1   = (const float*)d_in[5];
    const float* b1   = (const float*)d_in[6];
    const float* Wlk  = (const float*)d_in[7];
    const float* blkp = (const float*)d_in[8];
    const float* Wa   = (const float*)d_in[9];
    const float* ba   = (const float*)d_in[10];
    const int* esrc   = (const int*)d_in[11];
    const int* edst   = (const int*)d_in[12];
    float* out = (float*)d_out;

    char* ws = (char*)d_ws;
    size_t off = 0;
    float* Z  = (float*)(ws + off); off += (size_t)N_NODES * E_DIM * 4;
    f16* Ph   = (f16*)(ws + off);   off += (size_t)N_NODES * H0D * 2;
    f16* Pl   = (f16*)(ws + off);   off += (size_t)N_NODES * H0D * 2;
    f16* Qh   = (f16*)(ws + off);   off += (size_t)N_NODES * H0D * 2;
    f16* Ql   = (f16*)(ws + off);   off += (size_t)N_NODES * H0D * 2;
    // ---- contiguous zero-init region ----
    char* zero_base = ws + off;
    unsigned long long* keys  = (unsigned long long*)(ws + off); off += N_NODES * 8;
    unsigned long long* keys2 = (unsigned long long*)(ws + off); off += N_NODES * 8;
    int* tgt_writer = (int*)(ws + off); off += N_NODES * 4;   // +1 encoding, 0 = none
    int* seg_flag   = (int*)(ws + off); off += N_NODES * 4;
    int* count      = (int*)(ws + off); off += 128;
    size_t zero_bytes = (size_t)((ws + off) - zero_base);
    // -------------------------------------
    float* logits = (float*)(ws + off); off += (size_t)T_TOT * 2 * 4;
    float* lk_app = (float*)(ws + off); off += (size_t)T_TOT * 4;
    int* list     = (int*)(ws + off); off += (size_t)LIST_CAP * 4;
    int* chosen_arr = (int*)(ws + off); off += N_NODES * 4;
    f16* WeC_h = (f16*)(ws + off); off += (size_t)16 * 256 * 32 * 2;
    f16* WeC_l = (f16*)(ws + off); off += (size_t)16 * 256 * 32 * 2;
    f16* W1C_h = (f16*)(ws + off); off += (size_t)16 * 256 * 32 * 2;
    f16* W1C_l = (f16*)(ws + off); off += (size_t)16 * 256 * 32 * 2;
    f16* W0C_h = (f16*)(ws + off); off += (size_t)32 * 256 * 32 * 2;
    f16* W0C_l = (f16*)(ws + off); off += (size_t)32 * 256 * 32 * 2;

    hipMemsetAsync(zero_base, 0, zero_bytes, stream);

    k_prep_all<<<dim3(64), 256, 0, stream>>>(
        We, W1, W0, WeC_h, WeC_l, W1C_h, W1C_l, W0C_h, W0C_l);
    k1_split<<<dim3((N_NODES + 31) / 32), 256, 0, stream>>>(
        feat, WeC_h, WeC_l, be, Z, out);
    k2_split<<<dim3((N_NODES + 63) / 64, 4), 256, 0, stream>>>(
        out, W0C_h, W0C_l, b0, Ph, Pl, Qh, Ql);
    k3_f16<<<dim3((T_TOT + 63) / 64), 256, 0, stream>>>(
        Ph, Qh, W1C_h, b1, Wlk, blkp, Wa, ba, esrc, edst,
        keys, lk_app, logits);
    k_gb<<<dim3((T_TOT + 255) / 256), 256, 0, stream>>>(
        lk_app, keys, esrc, logits, seg_flag, list, count);
    k_fix2<<<dim3(FIX_GRID), 256, 0, stream>>>(
        Ph, Pl, Qh, Ql, W1C_h, W1C_l, b1, Wlk, blkp, Wa, ba,
        esrc, edst, list, count, keys2, logits);
    k4_select<<<dim3((N_NODES + 255) / 256), 256, 0, stream>>>(
        keys, keys2, edst, logits, chosen_arr, tgt_writer);
    k5_update<<<dim3(N_NODES), 256, 0, stream>>>(chosen_arr, tgt_writer, Z, out);
}